// Round 3
// baseline (631.148 us; speedup 1.0000x reference)
//
#include <hip/hip_runtime.h>

#define BB 256
#define TT 2048
#define KK 64
#define CHUNK 64
#define NCHUNK (TT / CHUNK)   // 32
#define NEG_INF_F (-10000.0f)

// DPP cross-lane helpers (free VALU permutes within 16-lane rows)
#define DPP_XOR1 0xB1   // quad_perm [1,0,3,2]
#define DPP_XOR2 0x4E   // quad_perm [2,3,0,1]
#define DPP_HMIR 0x141  // row_half_mirror (== xor4 once quads are reduced)

template <int CTRL>
__device__ __forceinline__ float dpp_f(float x) {
    return __int_as_float(__builtin_amdgcn_update_dpp(
        0, __float_as_int(x), CTRL, 0xF, 0xF, true));
}
template <int CTRL>
__device__ __forceinline__ int dpp_i(int x) {
    return __builtin_amdgcn_update_dpp(0, x, CTRL, 0xF, 0xF, true);
}

// LDS-only barrier: do NOT drain vmcnt (feat prefetches / bp stores stay in flight)
__device__ __forceinline__ void lds_barrier() {
    asm volatile("s_waitcnt lgkmcnt(0)\n\ts_barrier" ::: "memory");
}

__global__ __launch_bounds__(512, 2)
void viterbi_fwd_bt(const float* __restrict__ feats,
                    const float* __restrict__ trans,
                    const int* __restrict__ start_tag_p,
                    const int* __restrict__ stop_tag_p,
                    float* __restrict__ out,
                    unsigned char* __restrict__ bp_ws)
{
    const int b    = blockIdx.x;
    const int tid  = threadIdx.x;
    const int lane = tid & 63;
    const int w    = __builtin_amdgcn_readfirstlane(tid >> 6);  // wave id 0..7
    const int g    = lane >> 3;        // output-row group within wave
    const int j    = lane & 7;         // p-chunk within row
    const int n    = w * 8 + g;        // owned output row
    const int pbase = j * 8;           // first p of this lane's chunk

    const int start_tag = *start_tag_p;
    const int stop_tag  = *stop_tag_p;

    __shared__ float fv_lds[2][KK];    // double-buffered Viterbi variables
    __shared__ int   cmap[NCHUNK][KK]; // composed backpointer maps per chunk
    __shared__ int   be_lds[NCHUNK];
    __shared__ int   bl_lds;

    const float* fb = feats + (size_t)b * TT * KK;
    unsigned char* bpb = bp_ws + (size_t)b * TT * KK;

    // per-lane transition fragment: trans[n][pbase + i]
    float tr[8];
#pragma unroll
    for (int i = 0; i < 8; ++i) tr[i] = trans[n * KK + pbase + i];
    const float tstop = trans[stop_tag * KK + lane];

    const int p0 = pbase + 0, p1 = pbase + 1, p2 = pbase + 2, p3 = pbase + 3;
    const int p4 = pbase + 4, p5 = pbase + 5, p6 = pbase + 6, p7 = pbase + 7;

    if (tid < KK) fv_lds[0][tid] = (tid == start_tag) ? 0.0f : NEG_INF_F;
    __syncthreads();

    // feat prefetch ring (depth 4); only row n's value needed (8-lane broadcast)
    float r0 = fb[0 * KK + n];
    float r1 = fb[1 * KK + n];
    float r2 = fb[2 * KK + n];
    float r3 = fb[3 * KK + n];

    auto step = [&](int t, float featval) {
        // fv fragment (8-fold broadcast addresses; 2-way conflict = free)
        const float4* fp = (const float4*)&fv_lds[t & 1][pbase];
        const float4 fa = fp[0];
        const float4 fc = fp[1];

        const float v0 = fa.x + tr[0], v1 = fa.y + tr[1];
        const float v2 = fa.z + tr[2], v3 = fa.w + tr[3];
        const float v4 = fc.x + tr[4], v5 = fc.y + tr[5];
        const float v6 = fc.z + tr[6], v7 = fc.w + tr[7];

        // in-lane max (max3-friendly tree)
        const float ma = fmaxf(fmaxf(v0, v1), v2);
        const float mb = fmaxf(fmaxf(v3, v4), v5);
        const float mc = fmaxf(v6, v7);
        float m = fmaxf(fmaxf(ma, mb), mc);
        // cross-lane max over the 8 lanes sharing row n (free DPP)
        m = fmaxf(m, dpp_f<DPP_XOR1>(m));
        m = fmaxf(m, dpp_f<DPP_XOR2>(m));
        m = fmaxf(m, dpp_f<DPP_HMIR>(m));

        // argmax: equality select (parallel) + min tree (first-max tie-break)
        const int s0 = (v0 == m) ? p0 : 127;
        const int s1 = (v1 == m) ? p1 : 127;
        const int s2 = (v2 == m) ? p2 : 127;
        const int s3 = (v3 == m) ? p3 : 127;
        const int s4 = (v4 == m) ? p4 : 127;
        const int s5 = (v5 == m) ? p5 : 127;
        const int s6 = (v6 == m) ? p6 : 127;
        const int s7 = (v7 == m) ? p7 : 127;
        int idx = min(min(min(min(s0, s1), s2), min(min(s3, s4), s5)), min(s6, s7));
        idx = min(idx, dpp_i<DPP_XOR1>(idx));
        idx = min(idx, dpp_i<DPP_XOR2>(idx));
        idx = min(idx, dpp_i<DPP_HMIR>(idx));

        if (j == 0) {
            fv_lds[(t + 1) & 1][n] = m + featval;       // consecutive addrs
            bpb[(size_t)t * KK + n] = (unsigned char)idx;  // fire-and-forget byte
        }
        lds_barrier();
    };

    for (int t = 0; t < TT; t += 4) {
        float nr0 = fb[((t + 4 < TT) ? (t + 4) : (TT - 1)) * KK + n];
        step(t + 0, r0); r0 = nr0;
        float nr1 = fb[((t + 5 < TT) ? (t + 5) : (TT - 1)) * KK + n];
        step(t + 1, r1); r1 = nr1;
        float nr2 = fb[((t + 6 < TT) ? (t + 6) : (TT - 1)) * KK + n];
        step(t + 2, r2); r2 = nr2;
        float nr3 = fb[((t + 7 < TT) ? (t + 7) : (TT - 1)) * KK + n];
        step(t + 3, r3); r3 = nr3;
    }

    __syncthreads();   // full drain: all bp byte stores visible to the block

    // ---- chunk-map composition: wave w composes chunks 4w..4w+3 (post-pass) ----
    {
        const int c0 = w * 4;
        const unsigned char* q0 = bpb + (size_t)(c0 + 0) * CHUNK * KK + lane;
        const unsigned char* q1 = bpb + (size_t)(c0 + 1) * CHUNK * KK + lane;
        const unsigned char* q2 = bpb + (size_t)(c0 + 2) * CHUNK * KK + lane;
        const unsigned char* q3 = bpb + (size_t)(c0 + 3) * CHUNK * KK + lane;
        int M0 = lane, M1 = lane, M2 = lane, M3 = lane;
        int a0 = q0[0], a1 = q1[0], a2 = q2[0], a3 = q3[0];
        int b0 = q0[KK], b1 = q1[KK], b2 = q2[KK], b3 = q3[KK];
        for (int t = 0; t < CHUNK; t += 2) {
            int n0 = 0, n1 = 0, n2 = 0, n3 = 0, m0 = 0, m1 = 0, m2 = 0, m3 = 0;
            if (t + 2 < CHUNK) {
                n0 = q0[(t + 2) * KK]; n1 = q1[(t + 2) * KK];
                n2 = q2[(t + 2) * KK]; n3 = q3[(t + 2) * KK];
                m0 = q0[(t + 3) * KK]; m1 = q1[(t + 3) * KK];
                m2 = q2[(t + 3) * KK]; m3 = q3[(t + 3) * KK];
            }
            M0 = __shfl(M0, a0); M1 = __shfl(M1, a1);
            M2 = __shfl(M2, a2); M3 = __shfl(M3, a3);
            M0 = __shfl(M0, b0); M1 = __shfl(M1, b1);
            M2 = __shfl(M2, b2); M3 = __shfl(M3, b3);
            a0 = n0; a1 = n1; a2 = n2; a3 = n3;
            b0 = m0; b1 = m1; b2 = m2; b3 = m3;
        }
        cmap[c0 + 0][lane] = M0; cmap[c0 + 1][lane] = M1;
        cmap[c0 + 2][lane] = M2; cmap[c0 + 3][lane] = M3;
    }

    // ---- terminal argmax (wave 0, butterfly with first-max tie-break) ----
    if (w == 0) {
        float bv = fv_lds[TT & 1][lane] + tstop;   // TT even -> buffer 0
        int bi = lane;
#pragma unroll
        for (int off = 1; off < 64; off <<= 1) {
            const float ov = __shfl_xor(bv, off);
            const int   oi = __shfl_xor(bi, off);
            const bool take = (ov > bv) || (ov == bv && oi < bi);
            bv = take ? ov : bv;
            bi = take ? oi : bi;
        }
        if (lane == 0) { out[b] = bv; bl_lds = bi; }
    }
    __syncthreads();

    // ---- chunk-boundary tags via composed maps (serial, 32 LDS hops) ----
    if (tid == 0) {
        int x = bl_lds;
        be_lds[NCHUNK - 1] = x;
        for (int c = NCHUNK - 1; c >= 1; --c) {
            x = cmap[c][x];
            be_lds[c - 1] = x;
        }
    }
    __syncthreads();

    // ---- parallel interior backtrace (32 chunks, one lane each) ----
    if (tid < NCHUNK) {
        const int c = tid;
        int x = be_lds[c];
        float* po = out + BB + (size_t)b * TT;
        for (int t = (c + 1) * CHUNK - 1; t >= c * CHUNK; --t) {
            po[t] = (float)x;
            x = (int)bpb[(size_t)t * KK + x];
        }
    }
}

extern "C" void kernel_launch(void* const* d_in, const int* in_sizes, int n_in,
                              void* d_out, int out_size, void* d_ws, size_t ws_size,
                              hipStream_t stream) {
    const float* feats = (const float*)d_in[0];
    const float* trans = (const float*)d_in[1];
    const int* start_tag = (const int*)d_in[2];
    const int* stop_tag  = (const int*)d_in[3];
    float* out = (float*)d_out;
    unsigned char* bp = (unsigned char*)d_ws;   // B*T*K = 33.5 MB backpointers

    viterbi_fwd_bt<<<BB, 512, 0, stream>>>(feats, trans, start_tag, stop_tag, out, bp);
}